// Round 9
// baseline (666.080 us; speedup 1.0000x reference)
//
#include <hip/hip_runtime.h>

typedef unsigned short u16;
typedef unsigned int   u32;
typedef __attribute__((ext_vector_type(8))) short short8;   // 8 bf16 (4 VGPR)
typedef __attribute__((ext_vector_type(4))) float f32x4;

#define DEV static __device__ __forceinline__

DEV u16 f2bf(float f){                       // f32 -> bf16 RNE
  union { float f; u32 u; } v; v.f = f;
  u32 u = v.u;
  u += 0x7fffu + ((u >> 16) & 1u);
  return (u16)(u >> 16);
}
DEV float sigmoidf_(float x){ return 1.f / (1.f + __expf(-x)); }
DEV float tanh_fast(float x){ float e = __expf(2.f * x); return 1.f - 2.f / (e + 1.f); }

DEV void gload16(const void* g, void* l){    // async global->LDS, dest = uniform base + lane*16
  __builtin_amdgcn_global_load_lds(
      (const __attribute__((address_space(1))) void*)g,
      (__attribute__((address_space(3))) void*)l, 16, 0, 0);
}
DEV f32x4 mfma16(short8 a, short8 b, f32x4 c){
  return __builtin_amdgcn_mfma_f32_16x16x32_bf16(a, b, c, 0, 0, 0);
}
// 8 f32 -> short8 bf16 via v_cvt_pk_bf16_f32 (RNE; HW-verified R5-R8 absmax)
DEV short8 cvt8(float4 lo, float4 hi){
  union { u32 w[4]; short8 s; } r;
  asm("v_cvt_pk_bf16_f32 %0, %1, %2" : "=v"(r.w[0]) : "v"(lo.x), "v"(lo.y));
  asm("v_cvt_pk_bf16_f32 %0, %1, %2" : "=v"(r.w[1]) : "v"(lo.z), "v"(lo.w));
  asm("v_cvt_pk_bf16_f32 %0, %1, %2" : "=v"(r.w[2]) : "v"(hi.x), "v"(hi.y));
  asm("v_cvt_pk_bf16_f32 %0, %1, %2" : "=v"(r.w[3]) : "v"(hi.z), "v"(hi.w));
  return r.s;
}

// ---------------------------------------------------------------------------
// transpose + f32->bf16: src (K x N) f32  ->  dst (N x K) bf16
__global__ __launch_bounds__(256) void k_transpose_cvt(
    const float* __restrict__ src, u16* __restrict__ dst, int K, int N){
  __shared__ u16 t[64][72];
  int k0 = blockIdx.x << 6, n0 = blockIdx.y << 6;
  int tid = threadIdx.x;
  int r = tid >> 2, c0 = (tid & 3) << 4;
#pragma unroll
  for (int i = 0; i < 4; i++){
    float4 v = *(const float4*)&src[(size_t)(k0 + r) * N + n0 + c0 + i * 4];
    *(u32*)&t[r][c0 + i * 4 + 0] = (u32)f2bf(v.x) | ((u32)f2bf(v.y) << 16);
    *(u32*)&t[r][c0 + i * 4 + 2] = (u32)f2bf(v.z) | ((u32)f2bf(v.w) << 16);
  }
  __syncthreads();
  int n = tid >> 2, cc = (tid & 3) << 4;
  union { u16 s[16]; uint4 q[2]; } pk;
#pragma unroll
  for (int i = 0; i < 16; i++) pk.s[i] = t[cc + i][n];
  uint4* o = (uint4*)(dst + (size_t)(n0 + n) * K + k0 + cc);
  o[0] = pk.q[0]; o[1] = pk.q[1];
}

// ---------------------------------------------------------------------------
// q[b,u] = prevState[b,:] @ Ww[:,u] + bw[u] + bu[u]
__global__ __launch_bounds__(512) void k_q(
    const float* __restrict__ ps, const float* __restrict__ Ww,
    const float* __restrict__ bw, const float* __restrict__ bu,
    float* __restrict__ q){
  __shared__ float psl[16][512];
  int b0 = blockIdx.x << 4;
  int tid = threadIdx.x;
#pragma unroll
  for (int i = 0; i < 16; i++) psl[i][tid] = ps[(size_t)(b0 + i) * 512 + tid];
  __syncthreads();
  float acc[16];
#pragma unroll
  for (int i = 0; i < 16; i++) acc[i] = 0.f;
  for (int j = 0; j < 512; j++){
    float w = Ww[(size_t)j * 512 + tid];
#pragma unroll
    for (int i = 0; i < 16; i++) acc[i] = fmaf(psl[i][j], w, acc[i]);
  }
  float bias = bw[tid] + bu[tid];
#pragma unroll
  for (int i = 0; i < 16; i++) q[(size_t)(b0 + i) * 512 + tid] = acc[i] + bias;
}

// ---------------------------------------------------------------------------
__global__ __launch_bounds__(256) void k_gather(
    const int* __restrict__ tok, const float* __restrict__ emb, u16* __restrict__ xbf){
  int b = blockIdx.x, e = threadIdx.x;
  int t = tok[b];
  xbf[(size_t)b * 2304 + 2048 + e] = f2bf(emb[(size_t)t * 256 + e]);
}

// ---------------------------------------------------------------------------
__global__ __launch_bounds__(512) void k_bnprep(
    const float* __restrict__ gamma, const float* __restrict__ beta,
    const float* __restrict__ mmean, const float* __restrict__ mvar,
    const float* __restrict__ b1, float* __restrict__ bns, float* __restrict__ bno){
  int u = threadIdx.x;
  float sc = gamma[u] * rsqrtf(mvar[u] + 1e-3f);
  bns[u] = sc;
  bno[u] = (b1[u] - mmean[u]) * sc + beta[u];
}

// ---------------------------------------------------------------------------
// score v7 — OCCUPANCY experiment: wave-tile 64x64 (acc 64), tile 128M x 256N,
// launch_bounds(512,4) -> total regs <=128 -> 2 blocks/CU (R3-proven shape;
// R8 showed 1 block/CU kills HBM duty cycle). A: FM f32 staged via
// global_load_lds with SOURCE-swizzled chunks (linear LDS dest, rule 21);
// cvt_pk at read. B: WuT direct-from-L2 per-kh frags (16 live regs).
// N-siblings j, j+8 share a slab on the SAME XCD (R6-proven grouping).
// Epilogue: sp[nh][m] partial scores (R4-proven) -> k_softmax -> k_ctx.
__global__ __launch_bounds__(512, 4) void k_score(
    const float* __restrict__ fm, const u16* __restrict__ WuT,
    const float* __restrict__ q, const float* __restrict__ Wv,
    float* __restrict__ sp){
  __shared__ __align__(16) float Ab[2][128 * 64];   // 32 KB each (f32 tile)
  __shared__ float qsl[2][256];
  __shared__ float wvsl[256];
  __shared__ float part[128][4];

  int j = blockIdx.x;
  int slab = ((j >> 4) << 3) | (j & 7);            // j and j+8: same slab, same XCD
  int nh = (j >> 3) & 1;
  int n0 = nh << 8;                                 // 256-col half
  size_t gm0 = (size_t)slab << 7;                   // 128 rows = batches 2s,2s+1

  int tid = threadIdx.x, wid = tid >> 6, lane = tid & 63;
  int wm = wid >> 2, wn = wid & 3;
  int l15 = lane & 15, g = lane >> 4;

  qsl[tid >> 8][tid & 255] = q[(size_t)((slab << 1) + (tid >> 8)) * 512 + n0 + (tid & 255)];
  if (tid < 256) wvsl[tid] = Wv[n0 + tid];

  f32x4 acc[4][4];
#pragma unroll
  for (int i = 0; i < 4; i++)
#pragma unroll
    for (int jj = 0; jj < 4; jj++) acc[i][jj] = (f32x4){0.f, 0.f, 0.f, 0.f};

  // B row pointers: wave owns cols n0 + wn*64 .. +63
  const u16* brow[4];
#pragma unroll
  for (int ni = 0; ni < 4; ni++)
    brow[ni] = WuT + (size_t)(n0 + wn * 64 + ni * 16 + l15) * 2048 + g * 8;

  // A stage: tile 128x64 f32, 16 chunks(16B)/row, chunk c stored at slot
  // s = c ^ (r&15)  ->  source chunk for (r,s) is  c = s ^ (r&15).
  auto stage = [&](int t, int buf){
    int k0 = t << 6;
#pragma unroll
    for (int i = 0; i < 4; i++){
      int p = (i << 9) + tid;                       // flat 16B-chunk id 0..2047
      int r = p >> 4, s = p & 15;
      int c = s ^ (r & 15);
      gload16(fm + (gm0 + r) * 2048 + k0 + c * 4,
              (char*)Ab[buf] + (size_t)((i << 9) + (wid << 6)) * 16);
    }
  };
  auto computeStep = [&](int buf, int t){
    int k0 = t << 6;
#pragma unroll
    for (int kh = 0; kh < 2; kh++){
      short8 bfr[4], af[4];
#pragma unroll
      for (int ni = 0; ni < 4; ni++)
        bfr[ni] = *(const short8*)(brow[ni] + k0 + (kh << 5));
#pragma unroll
      for (int mi = 0; mi < 4; mi++){
        int r = wm * 64 + mi * 16 + l15;
        int c0 = (kh << 3) + (g << 1);
        int s0 = c0 ^ (r & 15), s1 = (c0 + 1) ^ (r & 15);
        float4 lo = *(const float4*)&Ab[buf][(r << 6) + (s0 << 2)];
        float4 hi = *(const float4*)&Ab[buf][(r << 6) + (s1 << 2)];
        af[mi] = cvt8(lo, hi);
      }
#pragma unroll
      for (int mi = 0; mi < 4; mi++)
#pragma unroll
        for (int ni = 0; ni < 4; ni++)
          acc[mi][ni] = mfma16(af[mi], bfr[ni], acc[mi][ni]);
    }
  };

  // main loop: dbuf, one barrier/step; 2 blocks/CU anti-phase hides the drain
  stage(0, 0);
  __syncthreads();
  int cur = 0;
  for (int t = 0; t < 32; t++){
    if (t < 31) stage(t + 1, cur ^ 1);
    computeStep(cur, t);
    __syncthreads();
    cur ^= 1;
  }

  // epilogue: partial score over this block's 256 cols
#pragma unroll
  for (int mi = 0; mi < 4; mi++)
#pragma unroll
    for (int jj = 0; jj < 4; jj++){
      int row = wm * 64 + mi * 16 + g * 4 + jj;
      float s = 0.f;
#pragma unroll
      for (int ni = 0; ni < 4; ni++){
        int col = wn * 64 + ni * 16 + l15;
        s += tanh_fast(acc[mi][ni][jj] + qsl[row >> 6][col]) * wvsl[col];
      }
      s += __shfl_xor(s, 1);
      s += __shfl_xor(s, 2);
      s += __shfl_xor(s, 4);
      s += __shfl_xor(s, 8);
      if (l15 == 0) part[row][wn] = s;
    }
  __syncthreads();
  if (tid < 128)
    sp[(size_t)nh * 65536 + gm0 + tid] =
        part[tid][0] + part[tid][1] + part[tid][2] + part[tid][3];
}

// ---------------------------------------------------------------------------
// softmax over L=64 per b: score = sum of 2 partials; attn -> d_out (f32)
__global__ __launch_bounds__(64) void k_softmax(
    const float* __restrict__ sp, float* __restrict__ attn_out){
  int b = blockIdx.x, l = threadIdx.x;
  size_t m = (size_t)b * 64 + l;
  float s = sp[m] + sp[65536 + m];
  float mx = s;
#pragma unroll
  for (int k = 32; k >= 1; k >>= 1) mx = fmaxf(mx, __shfl_xor(mx, k));
  float e = __expf(s - mx);
  float sum = e;
#pragma unroll
  for (int k = 32; k >= 1; k >>= 1) sum += __shfl_xor(sum, k);
  attn_out[m] = e / sum;
}

// ---------------------------------------------------------------------------
// ctx[b,:] = sum_l attn[b,l] * FM[b,l,:]  -> x_bf16[b, 0:2048]
__global__ __launch_bounds__(512) void k_ctx(
    const float* __restrict__ fm, const float* __restrict__ attn,
    u16* __restrict__ xbf){
  __shared__ float as_[64];
  int b = blockIdx.x, tid = threadIdx.x;
  if (tid < 64) as_[tid] = attn[(size_t)b * 64 + tid];
  __syncthreads();
  const float4* fmr = (const float4*)(fm + (size_t)b * (64 * 2048));
  float4 cx = {0.f, 0.f, 0.f, 0.f};
#pragma unroll 4
  for (int l = 0; l < 64; l++){
    float a = as_[l];
    float4 v = fmr[(size_t)l * 512 + tid];
    cx.x = fmaf(a, v.x, cx.x); cx.y = fmaf(a, v.y, cx.y);
    cx.z = fmaf(a, v.z, cx.z); cx.w = fmaf(a, v.w, cx.w);
  }
  uint2 o;
  o.x = (u32)f2bf(cx.x) | ((u32)f2bf(cx.y) << 16);
  o.y = (u32)f2bf(cx.z) | ((u32)f2bf(cx.w) << 16);
  *(uint2*)&xbf[(size_t)b * 2304 + tid * 4] = o;
}

// ---------------------------------------------------------------------------
// generic GEMM: C(MxN) = A(MxK bf16) @ Bt(NxK bf16)^T, epilogue scale/offset
template<bool OBF>
__global__ __launch_bounds__(512) void k_gemm(
    const u16* __restrict__ A, const u16* __restrict__ Bt,
    const float* __restrict__ scale, const float* __restrict__ off,
    void* __restrict__ Cout, int K, int N){
  __shared__ __align__(16) u16 Alds[2][128 * 64];
  __shared__ __align__(16) u16 Blds[2][128 * 64];
  int n0 = blockIdx.x << 7, m0 = blockIdx.y << 7;
  int tid = threadIdx.x, wid = tid >> 6, lane = tid & 63;
  int wm = wid >> 2, wn = wid & 3;

  f32x4 acc[4][2];
#pragma unroll
  for (int i = 0; i < 4; i++)
#pragma unroll
    for (int j = 0; j < 2; j++) acc[i][j] = (f32x4){0.f, 0.f, 0.f, 0.f};

  auto stage = [&](int s, int k0){
#pragma unroll
    for (int i = 0; i < 2; i++){
      int p = ((wid * 2 + i) << 6) + lane;
      int row = p >> 3, sl = p & 7, sl2 = sl ^ (row & 7);
      gload16(A  + (size_t)(m0 + row) * K + k0 + sl2 * 8,
              (char*)Alds[s] + (size_t)(wid * 2 + i) * 1024);
      gload16(Bt + (size_t)(n0 + row) * K + k0 + sl2 * 8,
              (char*)Blds[s] + (size_t)(wid * 2 + i) * 1024);
    }
  };

  int nk = K >> 6;
  stage(0, 0);
  __syncthreads();
  int cur = 0;
  for (int t = 0; t < nk; t++){
    if (t + 1 < nk) stage(cur ^ 1, (t + 1) << 6);
#pragma unroll
    for (int kh = 0; kh < 2; kh++){
      short8 af[4], bfr[2];
#pragma unroll
      for (int mi = 0; mi < 4; mi++){
        int r = wm * 64 + mi * 16 + (lane & 15);
        af[mi] = *(const short8*)&Alds[cur][r * 64 + (((kh << 2) + (lane >> 4)) ^ (r & 7)) * 8];
      }
#pragma unroll
      for (int ni = 0; ni < 2; ni++){
        int r = wn * 32 + ni * 16 + (lane & 15);
        bfr[ni] = *(const short8*)&Blds[cur][r * 64 + (((kh << 2) + (lane >> 4)) ^ (r & 7)) * 8];
      }
#pragma unroll
      for (int mi = 0; mi < 4; mi++)
#pragma unroll
        for (int ni = 0; ni < 2; ni++)
          acc[mi][ni] = mfma16(af[mi], bfr[ni], acc[mi][ni]);
    }
    __syncthreads();
    cur ^= 1;
  }
#pragma unroll
  for (int ni = 0; ni < 2; ni++){
    int n = n0 + wn * 32 + ni * 16 + (lane & 15);
    float sc = scale ? scale[n] : 1.f;
    float of = off ? off[n] : 0.f;
#pragma unroll
    for (int mi = 0; mi < 4; mi++)
#pragma unroll
      for (int j = 0; j < 4; j++){
        int m = m0 + wm * 64 + mi * 16 + (lane >> 4) * 4 + j;
        float v = acc[mi][ni][j] * sc + of;
        if (OBF) ((u16*)Cout)[(size_t)m * N + n] = f2bf(v);
        else     ((float*)Cout)[(size_t)m * N + n] = v;
      }
  }
}

// ---------------------------------------------------------------------------
__global__ __launch_bounds__(512) void k_gates(
    const float* __restrict__ xg, const float* __restrict__ gru_b,
    float* __restrict__ hout, u16* __restrict__ hbf){
  int b = blockIdx.x, u = threadIdx.x;
  const float* rg = gru_b + 1536;
  size_t base = (size_t)b * 1536;
  float z  = sigmoidf_(xg[base + u]        + rg[u]);
  float r  = sigmoidf_(xg[base + 512 + u]  + rg[512 + u]);
  float hh = tanh_fast(xg[base + 1024 + u] + r * rg[1024 + u]);
  float h = (1.f - z) * hh;
  hout[(size_t)b * 512 + u] = h;
  hbf[(size_t)b * 512 + u] = f2bf(h);
}

// ---------------------------------------------------------------------------
extern "C" void kernel_launch(void* const* d_in, const int* in_sizes, int n_in,
                              void* d_out, int out_size, void* d_ws, size_t ws_size,
                              hipStream_t stream){
  const int*   tok   = (const int*)  d_in[0];
  const float* fm    = (const float*)d_in[1];
  const float* ps    = (const float*)d_in[2];
  const float* emb   = (const float*)d_in[3];
  const float* Wu    = (const float*)d_in[4];
  const float* bu    = (const float*)d_in[5];
  const float* Ww    = (const float*)d_in[6];
  const float* bw    = (const float*)d_in[7];
  const float* Wv    = (const float*)d_in[8];
  // d_in[9] = bv: softmax-invariant, unused. d_in[11] = gru_rk: dead in reference.
  const float* gru_k = (const float*)d_in[10];
  const float* gru_b = (const float*)d_in[12];
  const float* W1    = (const float*)d_in[13];
  const float* b1    = (const float*)d_in[14];
  const float* gamma = (const float*)d_in[15];
  const float* beta  = (const float*)d_in[16];
  const float* mmean = (const float*)d_in[17];
  const float* mvar  = (const float*)d_in[18];
  const float* W2    = (const float*)d_in[19];
  const float* b2    = (const float*)d_in[20];

  float* logits = (float*)d_out;                     // 1024 x 32000
  float* hout   = (float*)d_out + 32768000;          // 1024 x 512
  float* attn   = (float*)d_out + 33292288;          // 1024 x 64

  char* ws = (char*)d_ws;
  u16*   WuT = (u16*)  (ws + 0);          // 512  x 2048 bf16
  u16*   gkT = (u16*)  (ws + 2097152);    // 1536 x 2304 bf16
  u16*   W2T = (u16*)  (ws + 9175040);    // 32000x 512  bf16
  u16*   W1T = (u16*)  (ws + 41943040);   // 512  x 512  bf16
  float* qws = (float*)(ws + 42467328);   // 1024 x 512  f32
  u16*   xbf = (u16*)  (ws + 44564480);   // 1024 x 2304 bf16
  float* xg  = (float*)(ws + 49283072);   // 1024 x 1536 f32
  u16*   hbf = (u16*)  (ws + 55574528);   // 1024 x 512  bf16
  u16*   ybf = (u16*)  (ws + 56623104);   // 1024 x 512  bf16
  float* bns = (float*)(ws + 57671680);   // 512 f32
  float* bno = (float*)(ws + 57673728);   // 512 f32
  float* sp  = xg;  // 2 x 65536 f32 aliases xg (consumed before xg written)

  k_transpose_cvt<<<dim3(32, 8),  256, 0, stream>>>(Wu,    WuT, 2048, 512);
  k_transpose_cvt<<<dim3(36, 24), 256, 0, stream>>>(gru_k, gkT, 2304, 1536);
  k_transpose_cvt<<<dim3(8, 500), 256, 0, stream>>>(W2,    W2T, 512,  32000);
  k_transpose_cvt<<<dim3(8, 8),   256, 0, stream>>>(W1,    W1T, 512,  512);
  k_q<<<64, 512, 0, stream>>>(ps, Ww, bw, bu, qws);
  k_gather<<<1024, 256, 0, stream>>>(tok, emb, xbf);
  k_bnprep<<<1, 512, 0, stream>>>(gamma, beta, mmean, mvar, b1, bns, bno);
  // attention: 2-blocks/CU score GEMM -> softmax -> ctx
  k_score<<<1024, 512, 0, stream>>>(fm, WuT, qws, Wv, sp);
  k_softmax<<<1024, 64, 0, stream>>>(sp, attn);
  k_ctx<<<1024, 512, 0, stream>>>(fm, attn, xbf);
  // xg = x @ gru_k + gru_b[0]
  k_gemm<false><<<dim3(12, 8), 512, 0, stream>>>(xbf, gkT, nullptr, gru_b, xg, 2304, 1536);
  k_gates<<<1024, 512, 0, stream>>>(xg, gru_b, hout, hbf);
  k_gemm<true><<<dim3(4, 8), 512, 0, stream>>>(hbf, W1T, bns, bno, ybf, 512, 512);
  k_gemm<false><<<dim3(250, 8), 512, 0, stream>>>(ybf, W2T, nullptr, b2, logits, 512, 32000);
}